// Round 8
// baseline (103.046 us; speedup 1.0000x reference)
//
#include <hip/hip_runtime.h>

// A5ExactScan: s_{t+1} = mul[x_t, s_t] over T=2048 per row (B=16384), s0=0.
// Radix-2 chain, [s][p]-layout 6-bit-packed pair table in LDS (bitpos =
// s*21600 + p*6, row stride 2700 B). On-chain per pair:
//   v_mad_u32_u24 -> ds_read2_b32 -> v_alignbit_b32 -> v_and  (~130 cy).
//
// Hard-won structure (rounds 2-7):
//  * amdgpu_waves_per_eu(1,1): REQUIRED (else ~20-VGPR budget, po/sh in
//    scratch, +120 cy/pair).
//  * sched_barrier(0) after load-issue: REQUIRED (else loads sink to their
//    consumers, exposing ~900 cy HBM latency; round 6 +13 us).
//  * [loads][SBAR][chain][SBAR][PREP+moves] is the best-measured schedule
//    (round 5); interleaving PREP inside the chain region regressed (round 7).
//  * THIS ROUND: K=2 independent chains per thread (rows tid and tid+8192),
//    PSTEPs interleaved pairwise. Chains are independent -> compiler's
//    counted lgkmcnt waits overlap the two ds_read latencies -> effective
//    per-pair latency ~halves. Grid: 128 blocks x 64 threads.

#define T_LEN 2048
#define NTOK 60
#define NPAIR (NTOK * NTOK)             // 3600
#define ROW_WORDS 675                   // 3600*6/32
#define NWORDS (NTOK * ROW_WORDS)       // 40500
#define ALLOC_WORDS (NWORDS + 4)        // pad: last entry reads word 40500
#define TAB_BYTES (ALLOC_WORDS * 4)     // 162016 B
#define BROWS 64
#define HALF_B 8192

// ---------------- kernel A: build packed [s][p] table in global scratch ----
__global__ void a5_build_kernel(const int* __restrict__ mul,
                                uint32_t* __restrict__ packed) {
  const int w = blockIdx.x * 256 + threadIdx.x;
  if (w >= ALLOC_WORDS) return;
  if (w >= NWORDS) { packed[w] = 0; return; }
  const uint32_t r = (uint32_t)w / ROW_WORDS;        // state s of this row
  const uint32_t woff = (uint32_t)w - r * ROW_WORDS; // word within row
  const uint32_t bit0 = woff * 32u;
  const uint32_t e0 = bit0 / 6u;
  const uint32_t sh0 = bit0 - e0 * 6u;
  uint64_t acc = 0;
#pragma unroll
  for (int k = 0; k < 7; ++k) {
    const uint32_t e = e0 + k;
    if (e < NPAIR) {
      const uint32_t x1 = e % 60u;
      const uint32_t x2 = e / 60u;
      const uint32_t v =
          (uint32_t)mul[x2 * 60u + (uint32_t)mul[x1 * 60u + r]];
      acc |= (uint64_t)v << (6 * k);
    }
  }
  packed[w] = (uint32_t)(acc >> sh0);
}

// ---------------- kernel B: two radix-2 chains per thread -------------------
__global__ __launch_bounds__(BROWS)
__attribute__((amdgpu_waves_per_eu(1, 1)))
void a5_scan2x2_kernel(const int* __restrict__ ids,
                       const uint32_t* __restrict__ packed,
                       float* __restrict__ out) {
  extern __shared__ uint32_t tab[];  // ALLOC_WORDS u32
  const int lane = threadIdx.x;

  // Fill LDS table (162 KB; L2/L3-hot after first blocks).
  {
    const uint4* s4 = (const uint4*)packed;
    uint4* d4 = (uint4*)tab;
#pragma unroll 4
    for (int i = lane; i < ALLOC_WORDS / 4; i += BROWS) d4[i] = s4[i];
  }
  __syncthreads();

  const int tid = blockIdx.x * BROWS + lane;  // 0..8191
  const int4* rpA = (const int4*)(ids + (size_t)tid * T_LEN);
  const int4* rpB = (const int4*)(ids + (size_t)(tid + HALF_B) * T_LEN);
  const char* tb = (const char*)tab;

  uint32_t sA = 0, sB = 0;  // states; s0 = identity id 0
  uint32_t poA[8], shA[8], poB[8], shB[8];

#define PREPC(PO, SH, J, X1, X2)                                  \
  do {                                                            \
    const uint32_t p6_ = (uint32_t)(X2)*360u + (uint32_t)(X1)*6u; \
    PO[J] = (p6_ >> 5) << 2;                                      \
    SH[J] = p6_ & 31u;                                            \
  } while (0)

#define PSTEPC(S, PO, SH, J)                                      \
  do {                                                            \
    const uint32_t a_ = S * 2700u + PO[J];                        \
    const uint32_t lo_ = *(const uint32_t*)(tb + a_);             \
    const uint32_t hi_ = *(const uint32_t*)(tb + a_ + 4);         \
    S = __builtin_amdgcn_alignbit(hi_, lo_, SH[J]) & 63u;         \
  } while (0)

  // Prologue: po/sh = pairs(block 0); n = tokens(block 1), both chains.
  int4 nA0, nA1, nA2, nA3, nB0, nB1, nB2, nB3;
  {
    int4 c0 = rpA[0], c1 = rpA[1], c2 = rpA[2], c3 = rpA[3];
    PREPC(poA, shA, 0, c0.x, c0.y); PREPC(poA, shA, 1, c0.z, c0.w);
    PREPC(poA, shA, 2, c1.x, c1.y); PREPC(poA, shA, 3, c1.z, c1.w);
    PREPC(poA, shA, 4, c2.x, c2.y); PREPC(poA, shA, 5, c2.z, c2.w);
    PREPC(poA, shA, 6, c3.x, c3.y); PREPC(poA, shA, 7, c3.z, c3.w);
    int4 d0 = rpB[0], d1 = rpB[1], d2 = rpB[2], d3 = rpB[3];
    PREPC(poB, shB, 0, d0.x, d0.y); PREPC(poB, shB, 1, d0.z, d0.w);
    PREPC(poB, shB, 2, d1.x, d1.y); PREPC(poB, shB, 3, d1.z, d1.w);
    PREPC(poB, shB, 4, d2.x, d2.y); PREPC(poB, shB, 5, d2.z, d2.w);
    PREPC(poB, shB, 6, d3.x, d3.y); PREPC(poB, shB, 7, d3.z, d3.w);
    nA0 = rpA[4]; nA1 = rpA[5]; nA2 = rpA[6]; nA3 = rpA[7];
    nB0 = rpB[4]; nB1 = rpB[5]; nB2 = rpB[6]; nB3 = rpB[7];
  }

  // Main loop: consume po/sh (block b), PREP block b+1 from n, load b+2.
  for (int b = 0; b <= 125; ++b) {
    const int4* mpA = rpA + (size_t)(b + 2) * 4;
    const int4* mpB = rpB + (size_t)(b + 2) * 4;
    int4 mA0 = mpA[0], mA1 = mpA[1], mA2 = mpA[2], mA3 = mpA[3];
    int4 mB0 = mpB[0], mB1 = mpB[1], mB2 = mpB[2], mB3 = mpB[3];
    __builtin_amdgcn_sched_barrier(0);  // pin load issue above the chains
    PSTEPC(sA, poA, shA, 0); PSTEPC(sB, poB, shB, 0);
    PSTEPC(sA, poA, shA, 1); PSTEPC(sB, poB, shB, 1);
    PSTEPC(sA, poA, shA, 2); PSTEPC(sB, poB, shB, 2);
    PSTEPC(sA, poA, shA, 3); PSTEPC(sB, poB, shB, 3);
    PSTEPC(sA, poA, shA, 4); PSTEPC(sB, poB, shB, 4);
    PSTEPC(sA, poA, shA, 5); PSTEPC(sB, poB, shB, 5);
    PSTEPC(sA, poA, shA, 6); PSTEPC(sB, poB, shB, 6);
    PSTEPC(sA, poA, shA, 7); PSTEPC(sB, poB, shB, 7);
    __builtin_amdgcn_sched_barrier(0);
    PREPC(poA, shA, 0, nA0.x, nA0.y); PREPC(poA, shA, 1, nA0.z, nA0.w);
    PREPC(poA, shA, 2, nA1.x, nA1.y); PREPC(poA, shA, 3, nA1.z, nA1.w);
    PREPC(poA, shA, 4, nA2.x, nA2.y); PREPC(poA, shA, 5, nA2.z, nA2.w);
    PREPC(poA, shA, 6, nA3.x, nA3.y); PREPC(poA, shA, 7, nA3.z, nA3.w);
    PREPC(poB, shB, 0, nB0.x, nB0.y); PREPC(poB, shB, 1, nB0.z, nB0.w);
    PREPC(poB, shB, 2, nB1.x, nB1.y); PREPC(poB, shB, 3, nB1.z, nB1.w);
    PREPC(poB, shB, 4, nB2.x, nB2.y); PREPC(poB, shB, 5, nB2.z, nB2.w);
    PREPC(poB, shB, 6, nB3.x, nB3.y); PREPC(poB, shB, 7, nB3.z, nB3.w);
    nA0 = mA0; nA1 = mA1; nA2 = mA2; nA3 = mA3;
    nB0 = mB0; nB1 = mB1; nB2 = mB2; nB3 = mB3;
  }
  // Epilogue: block 126 (in po/sh), then block 127 (PREP from n).
  PSTEPC(sA, poA, shA, 0); PSTEPC(sB, poB, shB, 0);
  PSTEPC(sA, poA, shA, 1); PSTEPC(sB, poB, shB, 1);
  PSTEPC(sA, poA, shA, 2); PSTEPC(sB, poB, shB, 2);
  PSTEPC(sA, poA, shA, 3); PSTEPC(sB, poB, shB, 3);
  PSTEPC(sA, poA, shA, 4); PSTEPC(sB, poB, shB, 4);
  PSTEPC(sA, poA, shA, 5); PSTEPC(sB, poB, shB, 5);
  PSTEPC(sA, poA, shA, 6); PSTEPC(sB, poB, shB, 6);
  PSTEPC(sA, poA, shA, 7); PSTEPC(sB, poB, shB, 7);
  PREPC(poA, shA, 0, nA0.x, nA0.y); PREPC(poA, shA, 1, nA0.z, nA0.w);
  PREPC(poA, shA, 2, nA1.x, nA1.y); PREPC(poA, shA, 3, nA1.z, nA1.w);
  PREPC(poA, shA, 4, nA2.x, nA2.y); PREPC(poA, shA, 5, nA2.z, nA2.w);
  PREPC(poA, shA, 6, nA3.x, nA3.y); PREPC(poA, shA, 7, nA3.z, nA3.w);
  PREPC(poB, shB, 0, nB0.x, nB0.y); PREPC(poB, shB, 1, nB0.z, nB0.w);
  PREPC(poB, shB, 2, nB1.x, nB1.y); PREPC(poB, shB, 3, nB1.z, nB1.w);
  PREPC(poB, shB, 4, nB2.x, nB2.y); PREPC(poB, shB, 5, nB2.z, nB2.w);
  PREPC(poB, shB, 6, nB3.x, nB3.y); PREPC(poB, shB, 7, nB3.z, nB3.w);
  PSTEPC(sA, poA, shA, 0); PSTEPC(sB, poB, shB, 0);
  PSTEPC(sA, poA, shA, 1); PSTEPC(sB, poB, shB, 1);
  PSTEPC(sA, poA, shA, 2); PSTEPC(sB, poB, shB, 2);
  PSTEPC(sA, poA, shA, 3); PSTEPC(sB, poB, shB, 3);
  PSTEPC(sA, poA, shA, 4); PSTEPC(sB, poB, shB, 4);
  PSTEPC(sA, poA, shA, 5); PSTEPC(sB, poB, shB, 5);
  PSTEPC(sA, poA, shA, 6); PSTEPC(sB, poB, shB, 6);
  PSTEPC(sA, poA, shA, 7); PSTEPC(sB, poB, shB, 7);
#undef PSTEPC
#undef PREPC

  // One-hot row writes for both rows (fully overwrite output).
  float4* opA = (float4*)(out + (size_t)tid * NTOK);
  float4* opB = (float4*)(out + (size_t)(tid + HALF_B) * NTOK);
#pragma unroll
  for (int j = 0; j < 15; ++j) {
    float4 v;
    v.x = ((uint32_t)(4 * j + 0) == sA) ? 5.0f : 0.0f;
    v.y = ((uint32_t)(4 * j + 1) == sA) ? 5.0f : 0.0f;
    v.z = ((uint32_t)(4 * j + 2) == sA) ? 5.0f : 0.0f;
    v.w = ((uint32_t)(4 * j + 3) == sA) ? 5.0f : 0.0f;
    opA[j] = v;
    float4 w;
    w.x = ((uint32_t)(4 * j + 0) == sB) ? 5.0f : 0.0f;
    w.y = ((uint32_t)(4 * j + 1) == sB) ? 5.0f : 0.0f;
    w.z = ((uint32_t)(4 * j + 2) == sB) ? 5.0f : 0.0f;
    w.w = ((uint32_t)(4 * j + 3) == sB) ? 5.0f : 0.0f;
    opB[j] = w;
  }
}

// ---------------- fallback: round-1 single-token chain ----------------------
__global__ __launch_bounds__(BROWS, 1) void a5_scan_kernel(
    const int* __restrict__ ids, const int* __restrict__ mul,
    float* __restrict__ out) {
  __shared__ uint32_t tab[NTOK * NTOK];
  const int lane = threadIdx.x;
  for (int i = lane; i < NTOK * NTOK; i += BROWS)
    tab[i] = ((uint32_t)mul[i]) << 2;
  __syncthreads();

  const int row = blockIdx.x * BROWS + lane;
  const int4* rp = (const int4*)(ids + (size_t)row * T_LEN);
  const char* tb = (const char*)tab;
  int4 c0 = rp[0], c1 = rp[1], c2 = rp[2], c3 = rp[3];
  uint32_t s4 = 0;
#define STEP(X)                                  \
  do {                                           \
    uint32_t base_ = (uint32_t)(X)*240u;         \
    s4 = *(const uint32_t*)(tb + base_ + s4);    \
  } while (0)
  for (int t = 0; t < T_LEN; t += 16) {
    int4 q0, q1, q2, q3;
    const bool more = (t + 16) < T_LEN;
    if (more) {
      const int4* np = rp + (t >> 2) + 4;
      q0 = np[0]; q1 = np[1]; q2 = np[2]; q3 = np[3];
    }
    STEP(c0.x); STEP(c0.y); STEP(c0.z); STEP(c0.w);
    STEP(c1.x); STEP(c1.y); STEP(c1.z); STEP(c1.w);
    STEP(c2.x); STEP(c2.y); STEP(c2.z); STEP(c2.w);
    STEP(c3.x); STEP(c3.y); STEP(c3.z); STEP(c3.w);
    if (more) { c0 = q0; c1 = q1; c2 = q2; c3 = q3; }
  }
#undef STEP
  const uint32_t s = s4 >> 2;
  float4* op = (float4*)(out + (size_t)row * NTOK);
#pragma unroll
  for (int j = 0; j < 15; ++j) {
    float4 v;
    v.x = ((uint32_t)(4 * j + 0) == s) ? 5.0f : 0.0f;
    v.y = ((uint32_t)(4 * j + 1) == s) ? 5.0f : 0.0f;
    v.z = ((uint32_t)(4 * j + 2) == s) ? 5.0f : 0.0f;
    v.w = ((uint32_t)(4 * j + 3) == s) ? 5.0f : 0.0f;
    op[j] = v;
  }
}

extern "C" void kernel_launch(void* const* d_in, const int* in_sizes, int n_in,
                              void* d_out, int out_size, void* d_ws,
                              size_t ws_size, hipStream_t stream) {
  const int* ids = (const int*)d_in[0];
  const int* mul = (const int*)d_in[1];
  float* out = (float*)d_out;
  const int B = in_sizes[0] / T_LEN;  // 16384

  if (ws_size >= (size_t)TAB_BYTES && B == 2 * HALF_B) {
    uint32_t* packed = (uint32_t*)d_ws;
    (void)hipFuncSetAttribute((const void*)a5_scan2x2_kernel,
                              hipFuncAttributeMaxDynamicSharedMemorySize,
                              TAB_BYTES);
    a5_build_kernel<<<(ALLOC_WORDS + 255) / 256, 256, 0, stream>>>(mul, packed);
    a5_scan2x2_kernel<<<HALF_B / BROWS, BROWS, TAB_BYTES, stream>>>(ids, packed,
                                                                    out);
  } else {
    a5_scan_kernel<<<B / BROWS, BROWS, 0, stream>>>(ids, mul, out);
  }
}

// Round 9
// 70.975 us; speedup vs baseline: 1.4519x; 1.4519x over previous
//
#include <hip/hip_runtime.h>

// A5ExactScan: s_{t+1} = mul[x_t, s_t] over T=2048 per row (B=16384), s0=0.
// Radix-2 chain, [s][p]-layout 6-bit-packed pair table in LDS (bitpos =
// s*21600 + p*6, row stride 2700 B).
//
// Structure ledger (rounds 2-8):
//  * amdgpu_waves_per_eu(1,1): REQUIRED (else ~20-VGPR budget, po/sh spill,
//    +120 cy/pair).
//  * sched_barrier(0) after token-load issue: REQUIRED (else loads sink,
//    exposing ~900 cy HBM latency per iter).
//  * K=2 chains/thread: DEAD (dispatch = per-wave serial time; doubling
//    per-wave slots loses more than ILP gains — round 8).
//  * Compiler scheduling of the PREP region: unreliable (rounds 6,7).
//  * THIS ROUND: the hop is fully inline-asm, split into ISSUE
//    (mad + 2x ds_read_b32) / PREP (5 VALUs for a next-block pair) /
//    CONSUME (s_waitcnt lgkmcnt(0) + alignbit + and). Volatile-asm order is
//    final order -> PREP executes inside the 120-cy LDS read shadow.
//    Ping-pong A/B pair-register sets kill the n=m moves.

#define T_LEN 2048
#define NTOK 60
#define NPAIR (NTOK * NTOK)             // 3600
#define ROW_WORDS 675                   // 3600*6/32
#define NWORDS (NTOK * ROW_WORDS)       // 40500
#define ALLOC_WORDS (NWORDS + 4)        // pad: last entry reads word 40500
#define TAB_BYTES (ALLOC_WORDS * 4)     // 162016 B
#define BROWS 64

// ---------------- kernel A: build packed [s][p] table in global scratch ----
__global__ void a5_build_kernel(const int* __restrict__ mul,
                                uint32_t* __restrict__ packed) {
  const int w = blockIdx.x * 256 + threadIdx.x;
  if (w >= ALLOC_WORDS) return;
  if (w >= NWORDS) { packed[w] = 0; return; }
  const uint32_t r = (uint32_t)w / ROW_WORDS;        // state s of this row
  const uint32_t woff = (uint32_t)w - r * ROW_WORDS; // word within row
  const uint32_t bit0 = woff * 32u;
  const uint32_t e0 = bit0 / 6u;
  const uint32_t sh0 = bit0 - e0 * 6u;
  uint64_t acc = 0;
#pragma unroll
  for (int k = 0; k < 7; ++k) {
    const uint32_t e = e0 + k;
    if (e < NPAIR) {
      const uint32_t x1 = e % 60u;
      const uint32_t x2 = e / 60u;
      const uint32_t v =
          (uint32_t)mul[x2 * 60u + (uint32_t)mul[x1 * 60u + r]];
      acc |= (uint64_t)v << (6 * k);
    }
  }
  packed[w] = (uint32_t)(acc >> sh0);
}

// ---------------- kernel B: per-row radix-2 chain, asm-scheduled hops -------
__global__ __launch_bounds__(BROWS)
__attribute__((amdgpu_waves_per_eu(1, 1)))
void a5_scan2_kernel(const int* __restrict__ ids,
                     const uint32_t* __restrict__ packed,
                     float* __restrict__ out) {
  extern __shared__ uint32_t tab[];  // ALLOC_WORDS u32, LDS offset 0
  const int lane = threadIdx.x;

  // Fill LDS table (162 KB; L2/L3-hot after first blocks).
  {
    const uint4* s4 = (const uint4*)packed;
    uint4* d4 = (uint4*)tab;
#pragma unroll 4
    for (int i = lane; i < ALLOC_WORDS / 4; i += BROWS) d4[i] = s4[i];
  }
  __syncthreads();

  const int row = blockIdx.x * BROWS + lane;
  const int4* rp = (const int4*)(ids + (size_t)row * T_LEN);

  // LDS byte base of tab (addrspacecast(3->0) low 32 bits = LDS offset).
  const uint32_t base = (uint32_t)(uintptr_t)(void*)tab;
  const uint32_t k2700 = 2700u;  // "s"-constrained -> hoisted s_mov

  uint32_t s = 0;  // state; s0 = identity id 0
  uint32_t poA[8], shA[8], poB[8], shB[8];
  uint32_t lo, hi, a;

  // ISSUE: a = s*2700 + po;  lo = LDS[a]; hi = LDS[a+4]
#define HOP_ISSUE(PO)                                             \
  asm volatile("v_mad_u32_u24 %2, %3, %4, %5\n\t"                 \
               "ds_read_b32 %0, %2\n\t"                           \
               "ds_read_b32 %1, %2 offset:4"                      \
               : "=&v"(lo), "=&v"(hi), "=&v"(a)                   \
               : "v"(s), "s"(k2700), "v"(PO))
  // PREP (inside the read shadow): p6=(x2*60+x1)*6; po=base+((p6>>5)<<2);
  // sh=p6&31. All inline-const operands; no literals in VOP3.
#define HOP_PREP(PO, SH, X1, X2)                                  \
  asm volatile("v_mad_u32_u24 %0, %3, 60, %2\n\t"                 \
               "v_mul_u32_u24 %0, 6, %0\n\t"                      \
               "v_and_b32 %1, 31, %0\n\t"                         \
               "v_lshrrev_b32 %0, 5, %0\n\t"                      \
               "v_lshl_add_u32 %0, %0, 2, %4"                     \
               : "=&v"(PO), "=&v"(SH)                             \
               : "v"((uint32_t)(X1)), "v"((uint32_t)(X2)), "v"(base))
  // CONSUME: wait both reads; s = ((hi:lo)>>sh) & 63
#define HOP_CONSUME(SH)                                           \
  asm volatile("s_waitcnt lgkmcnt(0)\n\t"                         \
               "v_alignbit_b32 %0, %2, %1, %3\n\t"                \
               "v_and_b32 %0, 63, %0"                             \
               : "=v"(s)                                          \
               : "v"(lo), "v"(hi), "v"(SH))

  // C-side prep for prologue/epilogue (same math, off the hot clock).
#define CPREP(PO, SH, X1, X2)                                         \
  do {                                                                \
    const uint32_t p6_ = ((uint32_t)(X2)*60u + (uint32_t)(X1)) * 6u;  \
    PO = base + ((p6_ >> 5) << 2);                                    \
    SH = p6_ & 31u;                                                   \
  } while (0)

  // Prologue: poA/shA = pairs(block 0); tA = tokens(block 1).
  int4 tA0, tA1, tA2, tA3, tB0, tB1, tB2, tB3;
  {
    int4 c0 = rp[0], c1 = rp[1], c2 = rp[2], c3 = rp[3];
    CPREP(poA[0], shA[0], c0.x, c0.y); CPREP(poA[1], shA[1], c0.z, c0.w);
    CPREP(poA[2], shA[2], c1.x, c1.y); CPREP(poA[3], shA[3], c1.z, c1.w);
    CPREP(poA[4], shA[4], c2.x, c2.y); CPREP(poA[5], shA[5], c2.z, c2.w);
    CPREP(poA[6], shA[6], c3.x, c3.y); CPREP(poA[7], shA[7], c3.z, c3.w);
    tA0 = rp[4]; tA1 = rp[5]; tA2 = rp[6]; tA3 = rp[7];
  }

  // Invariant at iter k: poA=pairs(k), tA=tokens(k+1).
  for (int k = 0; k <= 124; k += 2) {
    {  // half 1: load tokens(k+2)->tB; chain k via A; prep k+1 -> B from tA
      const int4* mp = rp + (size_t)(k + 2) * 4;
      tB0 = mp[0]; tB1 = mp[1]; tB2 = mp[2]; tB3 = mp[3];
      __builtin_amdgcn_sched_barrier(0);
      HOP_ISSUE(poA[0]); HOP_PREP(poB[0], shB[0], tA0.x, tA0.y); HOP_CONSUME(shA[0]);
      HOP_ISSUE(poA[1]); HOP_PREP(poB[1], shB[1], tA0.z, tA0.w); HOP_CONSUME(shA[1]);
      HOP_ISSUE(poA[2]); HOP_PREP(poB[2], shB[2], tA1.x, tA1.y); HOP_CONSUME(shA[2]);
      HOP_ISSUE(poA[3]); HOP_PREP(poB[3], shB[3], tA1.z, tA1.w); HOP_CONSUME(shA[3]);
      HOP_ISSUE(poA[4]); HOP_PREP(poB[4], shB[4], tA2.x, tA2.y); HOP_CONSUME(shA[4]);
      HOP_ISSUE(poA[5]); HOP_PREP(poB[5], shB[5], tA2.z, tA2.w); HOP_CONSUME(shA[5]);
      HOP_ISSUE(poA[6]); HOP_PREP(poB[6], shB[6], tA3.x, tA3.y); HOP_CONSUME(shA[6]);
      HOP_ISSUE(poA[7]); HOP_PREP(poB[7], shB[7], tA3.z, tA3.w); HOP_CONSUME(shA[7]);
    }
    {  // half 2: load tokens(k+3)->tA; chain k+1 via B; prep k+2 -> A from tB
      const int4* mq = rp + (size_t)(k + 3) * 4;
      tA0 = mq[0]; tA1 = mq[1]; tA2 = mq[2]; tA3 = mq[3];
      __builtin_amdgcn_sched_barrier(0);
      HOP_ISSUE(poB[0]); HOP_PREP(poA[0], shA[0], tB0.x, tB0.y); HOP_CONSUME(shB[0]);
      HOP_ISSUE(poB[1]); HOP_PREP(poA[1], shA[1], tB0.z, tB0.w); HOP_CONSUME(shB[1]);
      HOP_ISSUE(poB[2]); HOP_PREP(poA[2], shA[2], tB1.x, tB1.y); HOP_CONSUME(shB[2]);
      HOP_ISSUE(poB[3]); HOP_PREP(poA[3], shA[3], tB1.z, tB1.w); HOP_CONSUME(shB[3]);
      HOP_ISSUE(poB[4]); HOP_PREP(poA[4], shA[4], tB2.x, tB2.y); HOP_CONSUME(shB[4]);
      HOP_ISSUE(poB[5]); HOP_PREP(poA[5], shA[5], tB2.z, tB2.w); HOP_CONSUME(shB[5]);
      HOP_ISSUE(poB[6]); HOP_PREP(poA[6], shA[6], tB3.x, tB3.y); HOP_CONSUME(shB[6]);
      HOP_ISSUE(poB[7]); HOP_PREP(poA[7], shA[7], tB3.z, tB3.w); HOP_CONSUME(shB[7]);
    }
  }
  // Epilogue: poA=pairs(126), tA=tokens(127).
  HOP_ISSUE(poA[0]); HOP_PREP(poB[0], shB[0], tA0.x, tA0.y); HOP_CONSUME(shA[0]);
  HOP_ISSUE(poA[1]); HOP_PREP(poB[1], shB[1], tA0.z, tA0.w); HOP_CONSUME(shA[1]);
  HOP_ISSUE(poA[2]); HOP_PREP(poB[2], shB[2], tA1.x, tA1.y); HOP_CONSUME(shA[2]);
  HOP_ISSUE(poA[3]); HOP_PREP(poB[3], shB[3], tA1.z, tA1.w); HOP_CONSUME(shA[3]);
  HOP_ISSUE(poA[4]); HOP_PREP(poB[4], shB[4], tA2.x, tA2.y); HOP_CONSUME(shA[4]);
  HOP_ISSUE(poA[5]); HOP_PREP(poB[5], shB[5], tA2.z, tA2.w); HOP_CONSUME(shA[5]);
  HOP_ISSUE(poA[6]); HOP_PREP(poB[6], shB[6], tA3.x, tA3.y); HOP_CONSUME(shA[6]);
  HOP_ISSUE(poA[7]); HOP_PREP(poB[7], shB[7], tA3.z, tA3.w); HOP_CONSUME(shA[7]);
  HOP_ISSUE(poB[0]); HOP_CONSUME(shB[0]);
  HOP_ISSUE(poB[1]); HOP_CONSUME(shB[1]);
  HOP_ISSUE(poB[2]); HOP_CONSUME(shB[2]);
  HOP_ISSUE(poB[3]); HOP_CONSUME(shB[3]);
  HOP_ISSUE(poB[4]); HOP_CONSUME(shB[4]);
  HOP_ISSUE(poB[5]); HOP_CONSUME(shB[5]);
  HOP_ISSUE(poB[6]); HOP_CONSUME(shB[6]);
  HOP_ISSUE(poB[7]); HOP_CONSUME(shB[7]);
#undef HOP_ISSUE
#undef HOP_PREP
#undef HOP_CONSUME
#undef CPREP

  // One-hot row write: 15 x float4 = 60 floats, fully overwrites output.
  float4* op = (float4*)(out + (size_t)row * NTOK);
#pragma unroll
  for (int j = 0; j < 15; ++j) {
    float4 v;
    v.x = ((uint32_t)(4 * j + 0) == s) ? 5.0f : 0.0f;
    v.y = ((uint32_t)(4 * j + 1) == s) ? 5.0f : 0.0f;
    v.z = ((uint32_t)(4 * j + 2) == s) ? 5.0f : 0.0f;
    v.w = ((uint32_t)(4 * j + 3) == s) ? 5.0f : 0.0f;
    op[j] = v;
  }
}

// ---------------- fallback: round-1 single-token chain ----------------------
__global__ __launch_bounds__(BROWS, 1) void a5_scan_kernel(
    const int* __restrict__ ids, const int* __restrict__ mul,
    float* __restrict__ out) {
  __shared__ uint32_t tab[NTOK * NTOK];
  const int lane = threadIdx.x;
  for (int i = lane; i < NTOK * NTOK; i += BROWS)
    tab[i] = ((uint32_t)mul[i]) << 2;
  __syncthreads();

  const int row = blockIdx.x * BROWS + lane;
  const int4* rp = (const int4*)(ids + (size_t)row * T_LEN);
  const char* tb = (const char*)tab;
  int4 c0 = rp[0], c1 = rp[1], c2 = rp[2], c3 = rp[3];
  uint32_t s4 = 0;
#define STEP(X)                                  \
  do {                                           \
    uint32_t base_ = (uint32_t)(X)*240u;         \
    s4 = *(const uint32_t*)(tb + base_ + s4);    \
  } while (0)
  for (int t = 0; t < T_LEN; t += 16) {
    int4 q0, q1, q2, q3;
    const bool more = (t + 16) < T_LEN;
    if (more) {
      const int4* np = rp + (t >> 2) + 4;
      q0 = np[0]; q1 = np[1]; q2 = np[2]; q3 = np[3];
    }
    STEP(c0.x); STEP(c0.y); STEP(c0.z); STEP(c0.w);
    STEP(c1.x); STEP(c1.y); STEP(c1.z); STEP(c1.w);
    STEP(c2.x); STEP(c2.y); STEP(c2.z); STEP(c2.w);
    STEP(c3.x); STEP(c3.y); STEP(c3.z); STEP(c3.w);
    if (more) { c0 = q0; c1 = q1; c2 = q2; c3 = q3; }
  }
#undef STEP
  const uint32_t s = s4 >> 2;
  float4* op = (float4*)(out + (size_t)row * NTOK);
#pragma unroll
  for (int j = 0; j < 15; ++j) {
    float4 v;
    v.x = ((uint32_t)(4 * j + 0) == s) ? 5.0f : 0.0f;
    v.y = ((uint32_t)(4 * j + 1) == s) ? 5.0f : 0.0f;
    v.z = ((uint32_t)(4 * j + 2) == s) ? 5.0f : 0.0f;
    v.w = ((uint32_t)(4 * j + 3) == s) ? 5.0f : 0.0f;
    op[j] = v;
  }
}

extern "C" void kernel_launch(void* const* d_in, const int* in_sizes, int n_in,
                              void* d_out, int out_size, void* d_ws,
                              size_t ws_size, hipStream_t stream) {
  const int* ids = (const int*)d_in[0];
  const int* mul = (const int*)d_in[1];
  float* out = (float*)d_out;
  const int B = in_sizes[0] / T_LEN;  // 16384
  const int grid = B / BROWS;         // 256 blocks

  if (ws_size >= (size_t)TAB_BYTES) {
    uint32_t* packed = (uint32_t*)d_ws;
    (void)hipFuncSetAttribute((const void*)a5_scan2_kernel,
                              hipFuncAttributeMaxDynamicSharedMemorySize,
                              TAB_BYTES);
    a5_build_kernel<<<(ALLOC_WORDS + 255) / 256, 256, 0, stream>>>(mul, packed);
    a5_scan2_kernel<<<grid, BROWS, TAB_BYTES, stream>>>(ids, packed, out);
  } else {
    a5_scan_kernel<<<grid, BROWS, 0, stream>>>(ids, mul, out);
  }
}